// Round 9
// baseline (345.514 us; speedup 1.0000x reference)
//
#include <hip/hip_runtime.h>

// Problem constants (Qwen3MoE attention prefill)
#define B_   2
#define S_   1024
#define HID_ 2048
#define H_   32
#define HK_  4
#define D_   128
#define NQKV ((H_ + 2 * HK_) * D_)   // 5120
#define TOK  (B_ * S_)               // 2048

typedef short bf16x8  __attribute__((ext_vector_type(8)));  // 8 bf16 (4 VGPRs)
typedef short short4v __attribute__((ext_vector_type(4)));
typedef float f32x4   __attribute__((ext_vector_type(4)));
typedef int   i32x4   __attribute__((ext_vector_type(4)));

__device__ inline short f2bf(float f) {
  unsigned u = __builtin_bit_cast(unsigned, f);
  u += 0x7fffu + ((u >> 16) & 1u);   // round-to-nearest-even
  return (short)(u >> 16);
}
__device__ inline float bf2f(short s) {
  return __builtin_bit_cast(float, ((unsigned)(unsigned short)s) << 16);
}

// async global->LDS, 16B per lane; LDS dest is wave-uniform base + lane*16
__device__ __forceinline__ void gld_lds16(const short* g, short* l) {
  __builtin_amdgcn_global_load_lds((__attribute__((address_space(1))) void*)g,
                                   (__attribute__((address_space(3))) void*)l, 16, 0, 0);
}

// ---------------------------------------------------------------- cast fp32 -> bf16
__global__ __launch_bounds__(256) void cast_f32_bf16(const float* __restrict__ in,
                                                     short* __restrict__ out, int n4) {
  int i = blockIdx.x * 256 + threadIdx.x;
  if (i >= n4) return;
  f32x4 v = ((const f32x4*)in)[i];
  short4v o;
  o[0] = f2bf(v[0]); o[1] = f2bf(v[1]); o[2] = f2bf(v[2]); o[3] = f2bf(v[3]);
  ((short4v*)out)[i] = o;
}

// ---------------------------------------------------------------- transpose+cast: [K][N] f32 -> [N][K] bf16
__global__ __launch_bounds__(256) void transpose_cast(const float* __restrict__ in,
                                                      short* __restrict__ out,
                                                      int K, int N) {
  __shared__ float tile[32][33];
  int nb = blockIdx.x * 32, kb = blockIdx.y * 32;
  int c = threadIdx.x & 31, r0 = threadIdx.x >> 5;
#pragma unroll
  for (int i = 0; i < 4; i++) {
    int r = r0 + i * 8;
    tile[r][c] = in[(size_t)(kb + r) * N + nb + c];
  }
  __syncthreads();
#pragma unroll
  for (int i = 0; i < 4; i++) {
    int r = r0 + i * 8;
    out[(size_t)(nb + r) * K + kb + c] = f2bf(tile[c][r]);
  }
}

// ---------------------------------------------------------------- bf16 MFMA GEMM (m97 structure), split-K capable
__global__ __launch_bounds__(256) void gemm_bt128(const short* __restrict__ A,
                                                  const short* __restrict__ Bt,
                                                  float* __restrict__ C,
                                                  int M, int N, int Kfull, int klen) {
  const int tid  = threadIdx.x;
  const int m0   = blockIdx.y * 128;
  const int n0   = blockIdx.x * 128;
  const int kz0  = blockIdx.z * klen;
  const int w    = tid >> 6, lane = tid & 63;
  const int quad = lane >> 4, l16 = lane & 15;
  const int wm   = (w >> 1) * 64, wn = (w & 1) * 64;

  __shared__ short As[128 * 64];   // 16 KB, [row][64], chunks XOR-swizzled
  __shared__ short Bs[128 * 64];

  const f32x4 z = {0.f, 0.f, 0.f, 0.f};
  f32x4 acc[4][4];
#pragma unroll
  for (int i = 0; i < 4; i++)
#pragma unroll
    for (int j = 0; j < 4; j++) acc[i][j] = z;

  const int srow = lane >> 3;           // row within 8-row issue group
  const int lc   = (lane & 7) ^ srow;   // logical chunk this lane fetches

  for (int kk = 0; kk < klen; kk += 64) {
    const int k0 = kz0 + kk;
#pragma unroll
    for (int i = 0; i < 4; i++) {
      int rb = w * 32 + i * 8;
      gld_lds16(&A [(size_t)(m0 + rb + srow) * Kfull + k0 + lc * 8], &As[rb * 64]);
      gld_lds16(&Bt[(size_t)(n0 + rb + srow) * Kfull + k0 + lc * 8], &Bs[rb * 64]);
    }
    __syncthreads();
#pragma unroll
    for (int kb = 0; kb < 2; kb++) {
      const int pc = ((kb * 4 + quad) ^ (l16 & 7)) * 8;
      bf16x8 a[4], b[4];
#pragma unroll
      for (int f = 0; f < 4; f++) {
        a[f] = *(const bf16x8*)&As[(wm + f * 16 + l16) * 64 + pc];
        b[f] = *(const bf16x8*)&Bs[(wn + f * 16 + l16) * 64 + pc];
      }
#pragma unroll
      for (int fi = 0; fi < 4; fi++)
#pragma unroll
        for (int fj = 0; fj < 4; fj++)
          acc[fi][fj] = __builtin_amdgcn_mfma_f32_16x16x32_bf16(a[fi], b[fj], acc[fi][fj], 0, 0, 0);
    }
    __syncthreads();
  }

  float* Cz = C + (size_t)blockIdx.z * M * N;
#pragma unroll
  for (int fi = 0; fi < 4; fi++) {
    int row0 = m0 + wm + fi * 16 + quad * 4;
#pragma unroll
    for (int fj = 0; fj < 4; fj++) {
      int col = n0 + wn + fj * 16 + l16;
#pragma unroll
      for (int r = 0; r < 4; r++)
        Cz[(size_t)(row0 + r) * N + col] = acc[fi][fj][r];
    }
  }
}

// ---------------------------------------------------------------- split-K reduce: out = a + b
__global__ __launch_bounds__(256) void add2(const float* __restrict__ a,
                                            const float* __restrict__ b,
                                            float* __restrict__ c, int n4) {
  int i = blockIdx.x * 256 + threadIdx.x;
  if (i >= n4) return;
  f32x4 va = ((const f32x4*)a)[i], vb = ((const f32x4*)b)[i];
  ((f32x4*)c)[i] = va + vb;
}

// ---------------------------------------------------------------- fused QKV GEMM v2:
// C-tile (128 tokens x 1 head) in regs; epilogue does per-head RMSNorm + RoPE (q/k) or
// transposed store (v). Q/K path stages the bf16 tile through the dead As/Bs LDS
// (128x128 = exactly 32 KB, XOR chunk swizzle) so global stores are b128-coalesced and
// the RoPE d<->d^64 partner comes from the same tile (no separate exchange round).
__global__ __launch_bounds__(256) void gemm_qkv(const short* __restrict__ A,
                                                const short* __restrict__ Bt,
                                                const float* __restrict__ cosT,
                                                const float* __restrict__ sinT,
                                                const float* __restrict__ qw,
                                                const float* __restrict__ kw,
                                                short* __restrict__ Qb,
                                                short* __restrict__ Kb,
                                                short* __restrict__ Vt) {
  const int tid  = threadIdx.x;
  const int m0   = blockIdx.y * 128;
  const int n0   = blockIdx.x * 128;
  const int w    = tid >> 6, lane = tid & 63;
  const int quad = lane >> 4, l16 = lane & 15;
  const int wm   = (w >> 1) * 64, wn = (w & 1) * 64;

  __shared__ short smem[128 * 128];   // K-loop: As|Bs (16K each); epilogue: 128x128 bf16 tile
  short* As = smem;
  short* Bs = smem + 128 * 64;
  __shared__ float ss_lds[4][64];

  const f32x4 z = {0.f, 0.f, 0.f, 0.f};
  f32x4 acc[4][4];
#pragma unroll
  for (int i = 0; i < 4; i++)
#pragma unroll
    for (int j = 0; j < 4; j++) acc[i][j] = z;

  const int srow = lane >> 3;
  const int lc   = (lane & 7) ^ srow;

  for (int k0 = 0; k0 < HID_; k0 += 64) {
#pragma unroll
    for (int i = 0; i < 4; i++) {
      int rb = w * 32 + i * 8;
      gld_lds16(&A [(size_t)(m0 + rb + srow) * HID_ + k0 + lc * 8], &As[rb * 64]);
      gld_lds16(&Bt[(size_t)(n0 + rb + srow) * HID_ + k0 + lc * 8], &Bs[rb * 64]);
    }
    __syncthreads();
#pragma unroll
    for (int kb = 0; kb < 2; kb++) {
      const int pc = ((kb * 4 + quad) ^ (l16 & 7)) * 8;
      bf16x8 a[4], b[4];
#pragma unroll
      for (int f = 0; f < 4; f++) {
        a[f] = *(const bf16x8*)&As[(wm + f * 16 + l16) * 64 + pc];
        b[f] = *(const bf16x8*)&Bs[(wn + f * 16 + l16) * 64 + pc];
      }
#pragma unroll
      for (int fi = 0; fi < 4; fi++)
#pragma unroll
        for (int fj = 0; fj < 4; fj++)
          acc[fi][fj] = __builtin_amdgcn_mfma_f32_16x16x32_bf16(a[fi], b[fj], acc[fi][fj], 0, 0, 0);
    }
    __syncthreads();
  }

  // ---------------- fused epilogue ----------------
  const int hd = n0 >> 7;                 // head slot 0..39 (n-tile == one head)
  const int bb = m0 >> 10;                // batch (m-tiles never cross batch)
  const int s0 = m0 & (S_ - 1);

  if (hd >= H_ + HK_) {                   // ---- V head: bf16 transposed store [d][s]
    const int khv = hd - (H_ + HK_);
    short* dstV = Vt + ((size_t)(bb * HK_ + khv) * D_) * S_;
#pragma unroll
    for (int fi = 0; fi < 4; fi++) {
      int s = s0 + wm + fi * 16 + quad * 4;
#pragma unroll
      for (int fj = 0; fj < 4; fj++) {
        int d = wn + fj * 16 + l16;
        short4v o;
#pragma unroll
        for (int r = 0; r < 4; r++) o[r] = f2bf(acc[fi][fj][r]);
        *(short4v*)&dstV[(size_t)d * S_ + s] = o;
      }
    }
    return;
  }

  // ---- Q/K head: RMSNorm row sum-squares (each wave holds one d-half of rows wm..wm+63)
  float ssp[4][4];
#pragma unroll
  for (int fi = 0; fi < 4; fi++)
#pragma unroll
    for (int r = 0; r < 4; r++) {
      float t = 0.f;
#pragma unroll
      for (int fj = 0; fj < 4; fj++) t += acc[fi][fj][r] * acc[fi][fj][r];
      ssp[fi][r] = t;
    }
#pragma unroll
  for (int off = 1; off < 16; off <<= 1)
#pragma unroll
    for (int fi = 0; fi < 4; fi++)
#pragma unroll
      for (int r = 0; r < 4; r++) ssp[fi][r] += __shfl_xor(ssp[fi][r], off, 64);
  if (l16 == 0)
#pragma unroll
    for (int fi = 0; fi < 4; fi++)
#pragma unroll
      for (int r = 0; r < 4; r++) ss_lds[w][fi * 16 + quad * 4 + r] = ssp[fi][r];

  // ---- phase 1: y = acc*wgt -> bf16 tile T[row][128], chunk XOR (row&7) swizzle
  const float* wv = (hd < H_) ? qw : kw;
  float wgt[4];
#pragma unroll
  for (int fj = 0; fj < 4; fj++) wgt[fj] = wv[wn + fj * 16 + l16];
#pragma unroll
  for (int fj = 0; fj < 4; fj++) {
    const int chunk = (wn >> 3) + fj * 2 + (l16 >> 3);  // d>>3
    const int o = l16 & 7;
#pragma unroll
    for (int fi = 0; fi < 4; fi++)
#pragma unroll
      for (int r = 0; r < 4; r++) {
        int row = wm + fi * 16 + quad * 4 + r;
        smem[row * 128 + ((chunk ^ (row & 7)) << 3) + o] = f2bf(acc[fi][fj][r] * wgt[fj]);
      }
  }
  __syncthreads();

  // ---- phase 2: per (row, d-half) thread: rn + RoPE (partner from tile) + b128 stores
  const int row  = tid >> 1, half = tid & 1;
  const int rk   = row & 7;
  const int s    = s0 + row;
  const float ssrow = ss_lds[(row >> 6) * 2][row & 63] + ss_lds[(row >> 6) * 2 + 1][row & 63];
  const float osc = (hd < H_) ? (0.08838834764831845f * 1.4426950408889634f) : 1.0f;
  const float rno = rsqrtf(ssrow * (1.0f / 128.0f) + 1e-6f) * osc;
  const float sign = half ? 1.0f : -1.0f;
  short* dstQ = (hd < H_) ? (Qb + (((size_t)bb * H_ + hd) * S_) * D_)
                          : (Kb + (((size_t)bb * HK_ + (hd - H_)) * S_) * D_);
#pragma unroll
  for (int j = 0; j < 8; j++) {
    const int chunk = half * 8 + j;
    bf16x8 own = *(const bf16x8*)&smem[row * 128 + ((chunk ^ rk) << 3)];
    bf16x8 par = *(const bf16x8*)&smem[row * 128 + (((chunk ^ 8) ^ rk) << 3)];
    f32x4 c0  = *(const f32x4*)&cosT[(size_t)s * D_ + chunk * 8];
    f32x4 c1  = *(const f32x4*)&cosT[(size_t)s * D_ + chunk * 8 + 4];
    f32x4 sn0 = *(const f32x4*)&sinT[(size_t)s * D_ + chunk * 8];
    f32x4 sn1 = *(const f32x4*)&sinT[(size_t)s * D_ + chunk * 8 + 4];
    bf16x8 ov;
#pragma unroll
    for (int e = 0; e < 4; e++)
      ov[e] = f2bf(rno * (bf2f(own[e]) * c0[e] + sign * bf2f(par[e]) * sn0[e]));
#pragma unroll
    for (int e = 4; e < 8; e++)
      ov[e] = f2bf(rno * (bf2f(own[e]) * c1[e - 4] + sign * bf2f(par[e]) * sn1[e - 4]));
    *(bf16x8*)&dstQ[(size_t)s * D_ + chunk * 8] = ov;
  }
}

// ---------------------------------------------------------------- MFMA flash attention v5: static-max softmax
// |q.k*log2e| <= sqrt(D)*log2e = 16.3 (RMSNormed q,k) -> p = exp2(s-18): per-element
// softmax, no running max / rescale / shuffles; l via ones-rows in Vs.
__global__ __launch_bounds__(256) void attn_mfma5(const short* __restrict__ Qb,
                                                  const short* __restrict__ Kb,
                                                  const short* __restrict__ Vt,
                                                  short* __restrict__ ctx) {
  const int qmap[8] = {7, 0, 6, 1, 5, 2, 4, 3};   // adjacent pairs sum to 18 ktiles
  const int qt = qmap[blockIdx.x & 7];
  const int h  = blockIdx.y;
  const int b  = blockIdx.z;
  const int kh = h >> 3;          // G = 8
  const int q0 = qt * 128;
  const int tid = threadIdx.x, w = tid >> 6, lane = tid & 63;
  const int quad = lane >> 4, l16 = lane & 15;
  const float MBIAS = 18.0f;      // static softmax max (log2 units)

  __shared__ short Ks[128 * 64];        // K tile: row = key + 64*dhalf, XOR-swizzled
  __shared__ short Vs[144 * 64];        // V^T tile: row = d (128..143 = ones), XOR-swizzled
  __shared__ short Ps[4][2][16 * 72];   // per-(wave,fi) P [qrow][key]

  for (int i = tid; i < 16 * 64; i += 256) Vs[128 * 64 + i] = (short)0x3F80;

  const short* Qbase = Qb + (((size_t)b * H_ + h) * S_ + q0) * D_;
  bf16x8 aq[2][4];
#pragma unroll
  for (int fi = 0; fi < 2; fi++)
#pragma unroll
    for (int kb = 0; kb < 4; kb++)
      aq[fi][kb] = *(const bf16x8*)&Qbase[(size_t)(fi * 64 + w * 16 + l16) * D_ + kb * 32 + quad * 8];

  const f32x4 z = {0.f, 0.f, 0.f, 0.f};
  f32x4 O[2][9];                        // nb2=8 is the l column
#pragma unroll
  for (int fi = 0; fi < 2; fi++)
#pragma unroll
    for (int n = 0; n < 9; n++) O[fi][n] = z;

  const short* Kbase = Kb + ((size_t)(b * HK_ + kh) * S_) * D_;
  const short* Vbase = Vt + ((size_t)(b * HK_ + kh) * D_) * S_;

  const int srow = lane >> 3;
  const int lc   = (lane & 7) ^ srow;

  const int nkt = 2 * qt + 2;
  for (int kt = 0; kt < nkt; kt++) {
    const int k0 = kt * 64;
    __syncthreads();
#pragma unroll
    for (int i = 0; i < 4; i++) {
      int rb = w * 32 + i * 8;
      int rr = rb + srow;
      gld_lds16(&Kbase[(size_t)(k0 + (rr & 63)) * D_ + (rr >> 6) * 64 + lc * 8], &Ks[rb * 64]);
      gld_lds16(&Vbase[(size_t)rr * S_ + k0 + lc * 8], &Vs[rb * 64]);
    }
    __syncthreads();

    // ---- QK^T + static-max softmax + P write, nb-outer, bk shared across fi
#pragma unroll
    for (int nb = 0; nb < 4; nb++) {
      f32x4 s0 = z, s1 = z;
#pragma unroll
      for (int kb = 0; kb < 4; kb++) {
        const int c  = kb * 4 + quad;
        const int c7 = c & 7;
        const int rr = (c >> 3) * 64 + nb * 16 + l16;
        bf16x8 bk = *(const bf16x8*)&Ks[rr * 64 + (c7 ^ (l16 & 7)) * 8];
        s0 = __builtin_amdgcn_mfma_f32_16x16x32_bf16(aq[0][kb], bk, s0, 0, 0, 0);
        s1 = __builtin_amdgcn_mfma_f32_16x16x32_bf16(aq[1][kb], bk, s1, 0, 0, 0);
      }
      const int col = k0 + nb * 16 + l16;
#pragma unroll
      for (int r = 0; r < 4; r++) {
        int row0 = q0 + w * 16 + quad * 4 + r;
        float p0 = (col > row0) ? 0.0f : exp2f(s0[r] - MBIAS);
        float p1 = (col > row0 + 64) ? 0.0f : exp2f(s1[r] - MBIAS);
        Ps[w][0][(quad * 4 + r) * 72 + nb * 16 + l16] = f2bf(p0);
        Ps[w][1][(quad * 4 + r) * 72 + nb * 16 + l16] = f2bf(p1);
      }
    }

    // ---- PV: bv shared across fi; nb2=8 = ones -> l
#pragma unroll
    for (int kb2 = 0; kb2 < 2; kb2++) {
      bf16x8 ap0 = *(const bf16x8*)&Ps[w][0][l16 * 72 + kb2 * 32 + quad * 8];
      bf16x8 ap1 = *(const bf16x8*)&Ps[w][1][l16 * 72 + kb2 * 32 + quad * 8];
      const int c7 = kb2 * 4 + quad;
#pragma unroll
      for (int nb2 = 0; nb2 < 9; nb2++) {
        int d = nb2 * 16 + l16;
        bf16x8 bv = *(const bf16x8*)&Vs[d * 64 + (c7 ^ (d & 7)) * 8];
        O[0][nb2] = __builtin_amdgcn_mfma_f32_16x16x32_bf16(ap0, bv, O[0][nb2], 0, 0, 0);
        O[1][nb2] = __builtin_amdgcn_mfma_f32_16x16x32_bf16(ap1, bv, O[1][nb2], 0, 0, 0);
      }
    }
  }

  // ---- epilogue: O / l
#pragma unroll
  for (int fi = 0; fi < 2; fi++)
#pragma unroll
    for (int r = 0; r < 4; r++) {
      float inv = 1.0f / O[fi][8][r];
      size_t row = (size_t)(b * S_ + q0 + fi * 64 + w * 16 + quad * 4 + r);
      short* dst = ctx + row * (H_ * D_) + h * D_;
#pragma unroll
      for (int nb2 = 0; nb2 < 8; nb2++)
        dst[nb2 * 16 + l16] = f2bf(O[fi][nb2][r] * inv);
    }
}

// ---------------------------------------------------------------- launch
extern "C" void kernel_launch(void* const* d_in, const int* in_sizes, int n_in,
                              void* d_out, int out_size, void* d_ws, size_t ws_size,
                              hipStream_t stream) {
  (void)in_sizes; (void)n_in; (void)out_size; (void)ws_size;
  const float* hidden = (const float*)d_in[0];
  const float* cosT   = (const float*)d_in[1];
  const float* sinT   = (const float*)d_in[2];
  const float* wqkv   = (const float*)d_in[3];
  const float* qnw    = (const float*)d_in[4];
  const float* knw    = (const float*)d_in[5];
  const float* wo     = (const float*)d_in[6];
  float* out = (float*)d_out;

  char* ws = (char*)d_ws;
  short* Qb  = (short*)ws;                                    // 16 MB (dead after attn)
  short* Kb  = (short*)(ws + 16777216);                       //  2 MB
  short* Vt  = (short*)(ws + 16777216 + 2097152);             //  2 MB
  short* hb  = (short*)(ws + 41943040);                       //  8 MB hidden bf16
  short* wT  = (short*)(ws + 41943040 + 8388608);             // 20 MB w^T (qkv), then w_o^T
  short* ctx = (short*)(ws + 41943040 + 8388608 + 20971520);  // 16 MB ctx bf16
  float* part = (float*)ws;                                   // 32 MB split-K partials (over Qb/Kb/Vt, post-attn)

  // 1. hidden -> bf16
  cast_f32_bf16<<<4096, 256, 0, stream>>>(hidden, hb, TOK * HID_ / 4);
  // 2. w_qkv [2048][5120] -> bf16 [5120][2048]
  transpose_cast<<<dim3(NQKV / 32, HID_ / 32), 256, 0, stream>>>(wqkv, wT, HID_, NQKV);
  // 3. fused qkv-GEMM + RMSNorm + RoPE + V-transpose -> Qb/Kb/Vt bf16 (no fp32 qkv)
  gemm_qkv<<<dim3(NQKV / 128, TOK / 128), 256, 0, stream>>>(hb, wT, cosT, sinT, qnw, knw, Qb, Kb, Vt);
  // 4. MFMA causal GQA flash attention -> ctx bf16 [2048][4096]
  attn_mfma5<<<dim3(S_ / 128, H_, B_), 256, 0, stream>>>(Qb, Kb, Vt, ctx);
  // 5. w_o [4096][2048] -> bf16 [2048][4096]
  transpose_cast<<<dim3(HID_ / 32, (H_ * D_) / 32), 256, 0, stream>>>(wo, wT, H_ * D_, HID_);
  // 6. out = ctx @ w_o, split-K=2 (512 blocks -> 2/CU co-resident), then reduce
  gemm_bt128<<<dim3(HID_ / 128, TOK / 128, 2), 256, 0, stream>>>(ctx, wT, part, TOK, HID_, H_ * D_, (H_ * D_) / 2);
  add2<<<(TOK * HID_ / 4 + 255) / 256, 256, 0, stream>>>(part, part + (size_t)TOK * HID_, out, TOK * HID_ / 4);
}

// Round 10
// 334.160 us; speedup vs baseline: 1.0340x; 1.0340x over previous
//
#include <hip/hip_runtime.h>

// Problem constants (Qwen3MoE attention prefill)
#define B_   2
#define S_   1024
#define HID_ 2048
#define H_   32
#define HK_  4
#define D_   128
#define NQKV ((H_ + 2 * HK_) * D_)   // 5120
#define TOK  (B_ * S_)               // 2048

typedef short bf16x8  __attribute__((ext_vector_type(8)));  // 8 bf16 (4 VGPRs)
typedef short short4v __attribute__((ext_vector_type(4)));
typedef float f32x4   __attribute__((ext_vector_type(4)));
typedef int   i32x4   __attribute__((ext_vector_type(4)));

__device__ inline short f2bf(float f) {
  unsigned u = __builtin_bit_cast(unsigned, f);
  u += 0x7fffu + ((u >> 16) & 1u);   // round-to-nearest-even
  return (short)(u >> 16);
}
__device__ inline float bf2f(short s) {
  return __builtin_bit_cast(float, ((unsigned)(unsigned short)s) << 16);
}

// async global->LDS, 16B per lane; LDS dest is wave-uniform base + lane*16
__device__ __forceinline__ void gld_lds16(const short* g, short* l) {
  __builtin_amdgcn_global_load_lds((__attribute__((address_space(1))) void*)g,
                                   (__attribute__((address_space(3))) void*)l, 16, 0, 0);
}

// ---------------------------------------------------------------- cast fp32 -> bf16
__global__ __launch_bounds__(256) void cast_f32_bf16(const float* __restrict__ in,
                                                     short* __restrict__ out, int n4) {
  int i = blockIdx.x * 256 + threadIdx.x;
  if (i >= n4) return;
  f32x4 v = ((const f32x4*)in)[i];
  short4v o;
  o[0] = f2bf(v[0]); o[1] = f2bf(v[1]); o[2] = f2bf(v[2]); o[3] = f2bf(v[3]);
  ((short4v*)out)[i] = o;
}

// ---------------------------------------------------------------- transpose+cast: [K][N] f32 -> [N][K] bf16
__global__ __launch_bounds__(256) void transpose_cast(const float* __restrict__ in,
                                                      short* __restrict__ out,
                                                      int K, int N) {
  __shared__ float tile[32][33];
  int nb = blockIdx.x * 32, kb = blockIdx.y * 32;
  int c = threadIdx.x & 31, r0 = threadIdx.x >> 5;
#pragma unroll
  for (int i = 0; i < 4; i++) {
    int r = r0 + i * 8;
    tile[r][c] = in[(size_t)(kb + r) * N + nb + c];
  }
  __syncthreads();
#pragma unroll
  for (int i = 0; i < 4; i++) {
    int r = r0 + i * 8;
    out[(size_t)(nb + r) * K + kb + c] = f2bf(tile[c][r]);
  }
}

// ---------------------------------------------------------------- bf16 MFMA GEMM (m97 structure), split-K capable
__global__ __launch_bounds__(256) void gemm_bt128(const short* __restrict__ A,
                                                  const short* __restrict__ Bt,
                                                  float* __restrict__ C,
                                                  int M, int N, int Kfull, int klen) {
  const int tid  = threadIdx.x;
  const int m0   = blockIdx.y * 128;
  const int n0   = blockIdx.x * 128;
  const int kz0  = blockIdx.z * klen;
  const int w    = tid >> 6, lane = tid & 63;
  const int quad = lane >> 4, l16 = lane & 15;
  const int wm   = (w >> 1) * 64, wn = (w & 1) * 64;

  __shared__ short As[128 * 64];   // 16 KB, [row][64], chunks XOR-swizzled
  __shared__ short Bs[128 * 64];

  const f32x4 z = {0.f, 0.f, 0.f, 0.f};
  f32x4 acc[4][4];
#pragma unroll
  for (int i = 0; i < 4; i++)
#pragma unroll
    for (int j = 0; j < 4; j++) acc[i][j] = z;

  const int srow = lane >> 3;           // row within 8-row issue group
  const int lc   = (lane & 7) ^ srow;   // logical chunk this lane fetches

  for (int kk = 0; kk < klen; kk += 64) {
    const int k0 = kz0 + kk;
#pragma unroll
    for (int i = 0; i < 4; i++) {
      int rb = w * 32 + i * 8;
      gld_lds16(&A [(size_t)(m0 + rb + srow) * Kfull + k0 + lc * 8], &As[rb * 64]);
      gld_lds16(&Bt[(size_t)(n0 + rb + srow) * Kfull + k0 + lc * 8], &Bs[rb * 64]);
    }
    __syncthreads();
#pragma unroll
    for (int kb = 0; kb < 2; kb++) {
      const int pc = ((kb * 4 + quad) ^ (l16 & 7)) * 8;
      bf16x8 a[4], b[4];
#pragma unroll
      for (int f = 0; f < 4; f++) {
        a[f] = *(const bf16x8*)&As[(wm + f * 16 + l16) * 64 + pc];
        b[f] = *(const bf16x8*)&Bs[(wn + f * 16 + l16) * 64 + pc];
      }
#pragma unroll
      for (int fi = 0; fi < 4; fi++)
#pragma unroll
        for (int fj = 0; fj < 4; fj++)
          acc[fi][fj] = __builtin_amdgcn_mfma_f32_16x16x32_bf16(a[fi], b[fj], acc[fi][fj], 0, 0, 0);
    }
    __syncthreads();
  }

  float* Cz = C + (size_t)blockIdx.z * M * N;
#pragma unroll
  for (int fi = 0; fi < 4; fi++) {
    int row0 = m0 + wm + fi * 16 + quad * 4;
#pragma unroll
    for (int fj = 0; fj < 4; fj++) {
      int col = n0 + wn + fj * 16 + l16;
#pragma unroll
      for (int r = 0; r < 4; r++)
        Cz[(size_t)(row0 + r) * N + col] = acc[fi][fj][r];
    }
  }
}

// ---------------------------------------------------------------- split-K reduce: out = a + b
__global__ __launch_bounds__(256) void add2(const float* __restrict__ a,
                                            const float* __restrict__ b,
                                            float* __restrict__ c, int n4) {
  int i = blockIdx.x * 256 + threadIdx.x;
  if (i >= n4) return;
  f32x4 va = ((const f32x4*)a)[i], vb = ((const f32x4*)b)[i];
  ((f32x4*)c)[i] = va + vb;
}

// ---------------------------------------------------------------- fused QKV GEMM v3:
// For q/k head-blocks the MFMA operands are SWAPPED (A=weights, B=hidden), so the
// C-tile comes out d-major: each thread holds 4 contiguous d per token, with fi-row
// bases (w>>1)*16 + fi*32 so the RoPE partner d+64 is fi+2 IN THE SAME THREAD.
// RMSNorm+RoPE+store are then register-local: no LDS tile, no exchange, no barriers.
// V head-blocks keep normal operand order (token-major C -> [d][s] short4v stores).
__global__ __launch_bounds__(256) void gemm_qkv(const short* __restrict__ A,
                                                const short* __restrict__ Bt,
                                                const float* __restrict__ cosT,
                                                const float* __restrict__ sinT,
                                                const float* __restrict__ qw,
                                                const float* __restrict__ kw,
                                                short* __restrict__ Qb,
                                                short* __restrict__ Kb,
                                                short* __restrict__ Vt) {
  const int tid  = threadIdx.x;
  const int m0   = blockIdx.y * 128;
  const int n0   = blockIdx.x * 128;
  const int w    = tid >> 6, lane = tid & 63;
  const int quad = lane >> 4, l16 = lane & 15;

  const int hd   = n0 >> 7;               // head slot 0..39 (n-tile == one head)
  const bool isv = (hd >= H_ + HK_);

  __shared__ short As[128 * 64];
  __shared__ short Bs[128 * 64];
  __shared__ float ss_lds[2][128];

  const f32x4 z = {0.f, 0.f, 0.f, 0.f};
  f32x4 acc[4][4];
#pragma unroll
  for (int i = 0; i < 4; i++)
#pragma unroll
    for (int j = 0; j < 4; j++) acc[i][j] = z;

  const int srow = lane >> 3;
  const int lc   = (lane & 7) ^ srow;

  // fragment row bases: V-blocks = classic (A=hidden rows, B=weight rows);
  // QK-blocks = swapped (A-operand from Bs with stride-32 fi tiles, B-operand from As)
  const short* srcA = isv ? As : Bs;
  const short* srcB = isv ? Bs : As;
  int rA[4], rB[4];
#pragma unroll
  for (int f = 0; f < 4; f++) {
    rA[f] = isv ? ((w >> 1) * 64 + f * 16) : ((w >> 1) * 16 + f * 32);
    rB[f] = (w & 1) * 64 + f * 16;
  }

  for (int k0 = 0; k0 < HID_; k0 += 64) {
#pragma unroll
    for (int i = 0; i < 4; i++) {
      int rb = w * 32 + i * 8;
      gld_lds16(&A [(size_t)(m0 + rb + srow) * HID_ + k0 + lc * 8], &As[rb * 64]);
      gld_lds16(&Bt[(size_t)(n0 + rb + srow) * HID_ + k0 + lc * 8], &Bs[rb * 64]);
    }
    __syncthreads();
#pragma unroll
    for (int kb = 0; kb < 2; kb++) {
      const int pc = ((kb * 4 + quad) ^ (l16 & 7)) * 8;
      bf16x8 a[4], b[4];
#pragma unroll
      for (int f = 0; f < 4; f++) {
        a[f] = *(const bf16x8*)&srcA[(rA[f] + l16) * 64 + pc];
        b[f] = *(const bf16x8*)&srcB[(rB[f] + l16) * 64 + pc];
      }
#pragma unroll
      for (int fi = 0; fi < 4; fi++)
#pragma unroll
        for (int fj = 0; fj < 4; fj++)
          acc[fi][fj] = __builtin_amdgcn_mfma_f32_16x16x32_bf16(a[fi], b[fj], acc[fi][fj], 0, 0, 0);
    }
    __syncthreads();
  }

  // ---------------- fused epilogue ----------------
  const int bb = m0 >> 10;                // batch (m-tiles never cross batch)
  const int s0 = m0 & (S_ - 1);

  if (isv) {                              // ---- V head: rows=tokens, cols=d -> [d][s]
    const int khv = hd - (H_ + HK_);
    short* dstV = Vt + ((size_t)(bb * HK_ + khv) * D_) * S_;
#pragma unroll
    for (int fi = 0; fi < 4; fi++) {
      int s = s0 + (w >> 1) * 64 + fi * 16 + quad * 4;
#pragma unroll
      for (int fj = 0; fj < 4; fj++) {
        int d = (w & 1) * 64 + fj * 16 + l16;
        short4v o;
#pragma unroll
        for (int r = 0; r < 4; r++) o[r] = f2bf(acc[fi][fj][r]);
        *(short4v*)&dstV[(size_t)d * S_ + s] = o;
      }
    }
    return;
  }

  // ---- Q/K head (swapped): rows = d (fi-stride-32), cols = tokens ----
  // d(fi) = (w>>1)*16 + fi*32 + quad*4 + r ; token(fj) = (w&1)*64 + fj*16 + l16
  const int dqbase = (w >> 1) * 16 + quad * 4;

  // RMSNorm: per-token sum of squares. In-thread over 16 d's, then quad butterfly,
  // then combine the two wave-halves (w and w^2 hold complementary d-sets) via LDS.
  float ssp[4];
#pragma unroll
  for (int fj = 0; fj < 4; fj++) {
    float t = 0.f;
#pragma unroll
    for (int fi = 0; fi < 4; fi++)
#pragma unroll
      for (int r = 0; r < 4; r++) t += acc[fi][fj][r] * acc[fi][fj][r];
    ssp[fj] = t;
  }
#pragma unroll
  for (int fj = 0; fj < 4; fj++) {
    ssp[fj] += __shfl_xor(ssp[fj], 16, 64);
    ssp[fj] += __shfl_xor(ssp[fj], 32, 64);
  }
  if (quad == 0)
#pragma unroll
    for (int fj = 0; fj < 4; fj++)
      ss_lds[w >> 1][(w & 1) * 64 + fj * 16 + l16] = ssp[fj];
  __syncthreads();
  float rn[4];
#pragma unroll
  for (int fj = 0; fj < 4; fj++) {
    int t = (w & 1) * 64 + fj * 16 + l16;
    rn[fj] = rsqrtf((ss_lds[0][t] + ss_lds[1][t]) * (1.0f / 128.0f) + 1e-6f);
  }

  const float* wv = (hd < H_) ? qw : kw;
  f32x4 wgt[4];
#pragma unroll
  for (int fi = 0; fi < 4; fi++)
    wgt[fi] = *(const f32x4*)&wv[dqbase + fi * 32];

  const float osc = (hd < H_) ? (0.08838834764831845f * 1.4426950408889634f) : 1.0f;
  short* dstQ = (hd < H_) ? (Qb + (((size_t)bb * H_ + hd) * S_) * D_)
                          : (Kb + (((size_t)bb * HK_ + (hd - H_)) * S_) * D_);

#pragma unroll
  for (int f2 = 0; f2 < 2; f2++) {        // d pair: fi=f2 (d<64 half), fi=f2+2 (d+64)
    const int dlo = dqbase + f2 * 32;
#pragma unroll
    for (int fj = 0; fj < 4; fj++) {
      const int s = s0 + (w & 1) * 64 + fj * 16 + l16;
      f32x4 cl = *(const f32x4*)&cosT[(size_t)s * D_ + dlo];
      f32x4 sl = *(const f32x4*)&sinT[(size_t)s * D_ + dlo];
      f32x4 ch = *(const f32x4*)&cosT[(size_t)s * D_ + dlo + 64];
      f32x4 sh = *(const f32x4*)&sinT[(size_t)s * D_ + dlo + 64];
      short4v olo, ohi;
#pragma unroll
      for (int r = 0; r < 4; r++) {
        float y1 = acc[f2][fj][r]     * wgt[f2][r]     * rn[fj];
        float y2 = acc[f2 + 2][fj][r] * wgt[f2 + 2][r] * rn[fj];
        olo[r] = f2bf((y1 * cl[r] - y2 * sl[r]) * osc);
        ohi[r] = f2bf((y2 * ch[r] + y1 * sh[r]) * osc);
      }
      *(short4v*)&dstQ[(size_t)s * D_ + dlo]      = olo;
      *(short4v*)&dstQ[(size_t)s * D_ + dlo + 64] = ohi;
    }
  }
}

// ---------------------------------------------------------------- MFMA flash attention v5: static-max softmax
// |q.k*log2e| <= sqrt(D)*log2e = 16.3 (RMSNormed q,k) -> p = exp2(s-18): per-element
// softmax, no running max / rescale / shuffles; l via ones-rows in Vs.
__global__ __launch_bounds__(256) void attn_mfma5(const short* __restrict__ Qb,
                                                  const short* __restrict__ Kb,
                                                  const short* __restrict__ Vt,
                                                  short* __restrict__ ctx) {
  const int qmap[8] = {7, 0, 6, 1, 5, 2, 4, 3};   // adjacent pairs sum to 18 ktiles
  const int qt = qmap[blockIdx.x & 7];
  const int h  = blockIdx.y;
  const int b  = blockIdx.z;
  const int kh = h >> 3;          // G = 8
  const int q0 = qt * 128;
  const int tid = threadIdx.x, w = tid >> 6, lane = tid & 63;
  const int quad = lane >> 4, l16 = lane & 15;
  const float MBIAS = 18.0f;      // static softmax max (log2 units)

  __shared__ short Ks[128 * 64];        // K tile: row = key + 64*dhalf, XOR-swizzled
  __shared__ short Vs[144 * 64];        // V^T tile: row = d (128..143 = ones), XOR-swizzled
  __shared__ short Ps[4][2][16 * 72];   // per-(wave,fi) P [qrow][key]

  for (int i = tid; i < 16 * 64; i += 256) Vs[128 * 64 + i] = (short)0x3F80;

  const short* Qbase = Qb + (((size_t)b * H_ + h) * S_ + q0) * D_;
  bf16x8 aq[2][4];
#pragma unroll
  for (int fi = 0; fi < 2; fi++)
#pragma unroll
    for (int kb = 0; kb < 4; kb++)
      aq[fi][kb] = *(const bf16x8*)&Qbase[(size_t)(fi * 64 + w * 16 + l16) * D_ + kb * 32 + quad * 8];

  const f32x4 z = {0.f, 0.f, 0.f, 0.f};
  f32x4 O[2][9];                        // nb2=8 is the l column
#pragma unroll
  for (int fi = 0; fi < 2; fi++)
#pragma unroll
    for (int n = 0; n < 9; n++) O[fi][n] = z;

  const short* Kbase = Kb + ((size_t)(b * HK_ + kh) * S_) * D_;
  const short* Vbase = Vt + ((size_t)(b * HK_ + kh) * D_) * S_;

  const int srow = lane >> 3;
  const int lc   = (lane & 7) ^ srow;

  const int nkt = 2 * qt + 2;
  for (int kt = 0; kt < nkt; kt++) {
    const int k0 = kt * 64;
    __syncthreads();
#pragma unroll
    for (int i = 0; i < 4; i++) {
      int rb = w * 32 + i * 8;
      int rr = rb + srow;
      gld_lds16(&Kbase[(size_t)(k0 + (rr & 63)) * D_ + (rr >> 6) * 64 + lc * 8], &Ks[rb * 64]);
      gld_lds16(&Vbase[(size_t)rr * S_ + k0 + lc * 8], &Vs[rb * 64]);
    }
    __syncthreads();

    // ---- QK^T + static-max softmax + P write, nb-outer, bk shared across fi
#pragma unroll
    for (int nb = 0; nb < 4; nb++) {
      f32x4 s0 = z, s1 = z;
#pragma unroll
      for (int kb = 0; kb < 4; kb++) {
        const int c  = kb * 4 + quad;
        const int c7 = c & 7;
        const int rr = (c >> 3) * 64 + nb * 16 + l16;
        bf16x8 bk = *(const bf16x8*)&Ks[rr * 64 + (c7 ^ (l16 & 7)) * 8];
        s0 = __builtin_amdgcn_mfma_f32_16x16x32_bf16(aq[0][kb], bk, s0, 0, 0, 0);
        s1 = __builtin_amdgcn_mfma_f32_16x16x32_bf16(aq[1][kb], bk, s1, 0, 0, 0);
      }
      const int col = k0 + nb * 16 + l16;
#pragma unroll
      for (int r = 0; r < 4; r++) {
        int row0 = q0 + w * 16 + quad * 4 + r;
        float p0 = (col > row0) ? 0.0f : exp2f(s0[r] - MBIAS);
        float p1 = (col > row0 + 64) ? 0.0f : exp2f(s1[r] - MBIAS);
        Ps[w][0][(quad * 4 + r) * 72 + nb * 16 + l16] = f2bf(p0);
        Ps[w][1][(quad * 4 + r) * 72 + nb * 16 + l16] = f2bf(p1);
      }
    }

    // ---- PV: bv shared across fi; nb2=8 = ones -> l
#pragma unroll
    for (int kb2 = 0; kb2 < 2; kb2++) {
      bf16x8 ap0 = *(const bf16x8*)&Ps[w][0][l16 * 72 + kb2 * 32 + quad * 8];
      bf16x8 ap1 = *(const bf16x8*)&Ps[w][1][l16 * 72 + kb2 * 32 + quad * 8];
      const int c7 = kb2 * 4 + quad;
#pragma unroll
      for (int nb2 = 0; nb2 < 9; nb2++) {
        int d = nb2 * 16 + l16;
        bf16x8 bv = *(const bf16x8*)&Vs[d * 64 + (c7 ^ (d & 7)) * 8];
        O[0][nb2] = __builtin_amdgcn_mfma_f32_16x16x32_bf16(ap0, bv, O[0][nb2], 0, 0, 0);
        O[1][nb2] = __builtin_amdgcn_mfma_f32_16x16x32_bf16(ap1, bv, O[1][nb2], 0, 0, 0);
      }
    }
  }

  // ---- epilogue: O / l
#pragma unroll
  for (int fi = 0; fi < 2; fi++)
#pragma unroll
    for (int r = 0; r < 4; r++) {
      float inv = 1.0f / O[fi][8][r];
      size_t row = (size_t)(b * S_ + q0 + fi * 64 + w * 16 + quad * 4 + r);
      short* dst = ctx + row * (H_ * D_) + h * D_;
#pragma unroll
      for (int nb2 = 0; nb2 < 8; nb2++)
        dst[nb2 * 16 + l16] = f2bf(O[fi][nb2][r] * inv);
    }
}

// ---------------------------------------------------------------- launch
extern "C" void kernel_launch(void* const* d_in, const int* in_sizes, int n_in,
                              void* d_out, int out_size, void* d_ws, size_t ws_size,
                              hipStream_t stream) {
  (void)in_sizes; (void)n_in; (void)out_size; (void)ws_size;
  const float* hidden = (const float*)d_in[0];
  const float* cosT   = (const float*)d_in[1];
  const float* sinT   = (const float*)d_in[2];
  const float* wqkv   = (const float*)d_in[3];
  const float* qnw    = (const float*)d_in[4];
  const float* knw    = (const float*)d_in[5];
  const float* wo     = (const float*)d_in[6];
  float* out = (float*)d_out;

  char* ws = (char*)d_ws;
  short* Qb  = (short*)ws;                                    // 16 MB (dead after attn)
  short* Kb  = (short*)(ws + 16777216);                       //  2 MB
  short* Vt  = (short*)(ws + 16777216 + 2097152);             //  2 MB
  short* hb  = (short*)(ws + 41943040);                       //  8 MB hidden bf16
  short* wT  = (short*)(ws + 41943040 + 8388608);             // 20 MB w^T (qkv), then w_o^T
  short* ctx = (short*)(ws + 41943040 + 8388608 + 20971520);  // 16 MB ctx bf16
  float* part = (float*)ws;                                   // 32 MB split-K partials (over Qb/Kb/Vt, post-attn)

  // 1. hidden -> bf16
  cast_f32_bf16<<<4096, 256, 0, stream>>>(hidden, hb, TOK * HID_ / 4);
  // 2. w_qkv [2048][5120] -> bf16 [5120][2048]
  transpose_cast<<<dim3(NQKV / 32, HID_ / 32), 256, 0, stream>>>(wqkv, wT, HID_, NQKV);
  // 3. fused qkv-GEMM + RMSNorm + RoPE + V-transpose -> Qb/Kb/Vt bf16 (no fp32 qkv)
  gemm_qkv<<<dim3(NQKV / 128, TOK / 128), 256, 0, stream>>>(hb, wT, cosT, sinT, qnw, knw, Qb, Kb, Vt);
  // 4. MFMA causal GQA flash attention -> ctx bf16 [2048][4096]
  attn_mfma5<<<dim3(S_ / 128, H_, B_), 256, 0, stream>>>(Qb, Kb, Vt, ctx);
  // 5. w_o [4096][2048] -> bf16 [2048][4096]
  transpose_cast<<<dim3(HID_ / 32, (H_ * D_) / 32), 256, 0, stream>>>(wo, wT, H_ * D_, HID_);
  // 6. out = ctx @ w_o, split-K=2 (512 blocks -> 2/CU co-resident), then reduce
  gemm_bt128<<<dim3(HID_ / 128, TOK / 128, 2), 256, 0, stream>>>(ctx, wT, part, TOK, HID_, H_ * D_, (H_ * D_) / 2);
  add2<<<(TOK * HID_ / 4 + 255) / 256, 256, 0, stream>>>(part, part + (size_t)TOK * HID_, out, TOK * HID_ / 4);
}